// Round 5
// baseline (172.556 us; speedup 1.0000x reference)
//
#include <hip/hip_runtime.h>
#include <hip/hip_bf16.h>

#define NPOS 4096
#define CDIM 64
#define BATCH 2
#define JSPLIT 8                  // j-range split; Opart = 8.4 MB bf16
#define JSHIFT 3                  // log2(JSPLIT)
#define JCHUNK (NPOS / JSPLIT)    // 512 j per block (8 tiles of 64)
#define NTILE (JCHUNK / 64)       // 8 pipelined tiles
#define RPB 64                    // q-rows per block (4 waves x 16 rows)
#define NGROUP (BATCH * (NPOS / RPB))               // 128 (b,rb) groups
#define ATTN_GRID (BATCH * (NPOS / RPB) * JSPLIT)   // 1024 blocks

typedef __attribute__((ext_vector_type(8))) short bf16x8;
typedef __attribute__((ext_vector_type(4))) short short4b;
typedef __attribute__((ext_vector_type(4))) float f32x4;
typedef __attribute__((ext_vector_type(4))) unsigned int u32x4;
typedef __attribute__((ext_vector_type(2))) unsigned int u32x2;

static __device__ __forceinline__ unsigned int fbits(float f) {
    union { float f; unsigned int u; } v; v.f = f; return v.u;
}
static __device__ __forceinline__ float bffloat(unsigned int hi16) {
    union { unsigned int u; float f; } v; v.u = hi16; return v.f;
}
static __device__ __forceinline__ unsigned int pk2bf(float a, float b) {
    return ((fbits(a) + 0x8000u) >> 16) | ((fbits(b) + 0x8000u) & 0xffff0000u);
}
static __device__ __forceinline__ short f2bs(float f) {
    return (short)(unsigned short)((fbits(f) + 0x8000u) >> 16);
}

// async global->LDS, 16B per lane; LDS dest = wave-uniform base + lane*16,
// global src is per-lane (carries the XOR swizzle).
static __device__ __forceinline__ void gload16(const void* g, void* l) {
    __builtin_amdgcn_global_load_lds(
        (const __attribute__((address_space(1))) unsigned int*)g,
        (__attribute__((address_space(3))) unsigned int*)l, 16, 0, 0);
}

// ---------------------------------------------------------------------------
// Kernel 1: qkv with weff fused in-register (verified math, unchanged).
// Also zeroes the 128 group-completion counters (block 0) — runs strictly
// before attn on the stream, so per-iteration workspace poison is cleared.
// MFMA 16x16x32 bf16 layouts (HW-verified):
//   A[m=lane&15][k=quad*8+j]  B[k=quad*8+j][n=lane&15]  C/D[quad*4+r][lane&15]
// ---------------------------------------------------------------------------
__global__ __launch_bounds__(64) void qkv_kernel(
    const float* __restrict__ x,
    const float* __restrict__ q_dw, const float* __restrict__ q_pw,
    const float* __restrict__ k_dw, const float* __restrict__ k_pw,
    const float* __restrict__ v_dw, const float* __restrict__ v_pw,
    short* __restrict__ qT, short* __restrict__ kT, short* __restrict__ vM,
    int* __restrict__ cnt)
{
    const int bid  = blockIdx.x;
    const int lane = threadIdx.x;
    if (bid == 0) {                    // zero group counters (128 = 2 per lane)
        cnt[lane] = 0;
        cnt[lane + 64] = 0;
    }
    const int p    = bid >> 9;          // 0=q 1=k 2=v
    const int np   = bid & 511;
    const int b    = np >> 8;
    const int n0   = (np & 255) << 4;
    const int col  = lane & 15;
    const int quad = lane >> 4;
    const int n    = n0 + col;

    const float* pw = (p == 0) ? q_pw : (p == 1) ? k_pw : v_pw;
    const float* dw = (p == 0) ? q_dw : (p == 1) ? k_dw : v_dw;

    bf16x8 xf0, xf1;
    float dv0[8], dv1[8];
    #pragma unroll
    for (int j = 0; j < 8; ++j) {
        xf0[j] = f2bs(x[(size_t)(b * CDIM + quad * 8 + j) * NPOS + n]);
        xf1[j] = f2bs(x[(size_t)(b * CDIM + 32 + quad * 8 + j) * NPOS + n]);
        dv0[j] = dw[quad * 8 + j];
        dv1[j] = dw[32 + quad * 8 + j];
    }

    #pragma unroll
    for (int os = 0; os < 4; ++os) {
        const float* pr = pw + (os * 16 + col) * 64 + quad * 8;
        bf16x8 wf0, wf1;
        #pragma unroll
        for (int j = 0; j < 8; ++j) {
            wf0[j] = f2bs(pr[j] * dv0[j]);
            wf1[j] = f2bs(pr[32 + j] * dv1[j]);
        }
        f32x4 d = (f32x4){0.f, 0.f, 0.f, 0.f};
        if (p < 2) {
            d = __builtin_amdgcn_mfma_f32_16x16x32_bf16(wf0, xf0, d, 0, 0, 0);
            d = __builtin_amdgcn_mfma_f32_16x16x32_bf16(wf1, xf1, d, 0, 0, 0);
            short* dst = p ? kT : qT;
            *(u32x2*)(dst + (size_t)(b * NPOS + n) * CDIM + os * 16 + quad * 4) =
                (u32x2){pk2bf(d[0], d[1]), pk2bf(d[2], d[3])};
        } else {
            d = __builtin_amdgcn_mfma_f32_16x16x32_bf16(xf0, wf0, d, 0, 0, 0);
            d = __builtin_amdgcn_mfma_f32_16x16x32_bf16(xf1, wf1, d, 0, 0, 0);
            *(u32x2*)(vM + (size_t)(b * CDIM + os * 16 + col) * NPOS + n0 + quad * 4) =
                (u32x2){pk2bf(d[0], d[1]), pk2bf(d[2], d[3])};
        }
    }
}

// ---------------------------------------------------------------------------
// Kernel 2: flash attention v6 = R2-verified body + fused combine tail.
// Last-block-done pattern: each (b,rb) group has JSPLIT=8 blocks; writers do
// stores -> syncthreads -> threadfence(release, wbL2) -> atomicAdd(LLC).
// The 8th block threadfence(acquire, invL2 — mandatory: XCD L2s are not
// coherent and the workspace-fill kernel may have left stale lines), then
// re-reads all 8 Opart partials + lacc and writes out directly. linv/flag
// alias the dead Pw LDS so LDS stays 40960 (4 blocks/CU preserved).
// Reduction order identical to the old combine kernel => bit-identical out.
// ---------------------------------------------------------------------------
__global__ __launch_bounds__(256, 4) void attn_kernel(
    const short* __restrict__ qT, const short* __restrict__ kT,
    const short* __restrict__ vM,
    unsigned short* __restrict__ Opart, float* __restrict__ lacc,
    int* __restrict__ cnt,
    const float* __restrict__ x, const float* __restrict__ gamma,
    float* __restrict__ out)
{
    const int gid  = blockIdx.x;
    const int jc   = gid & (JSPLIT - 1);
    const int rb   = (gid >> JSHIFT) & 63;
    const int b    = gid >> (JSHIFT + 6);
    const int t    = threadIdx.x;
    const int wave = t >> 6;
    const int lane = t & 63;
    const int col  = lane & 15;
    const int quad = lane >> 4;

    __shared__ __align__(16) short Kbuf[2][64 * 64];   // [j-in-tile][ch], 128B rows
    __shared__ __align__(16) short Vbuf[2][64 * 64];   // [ch][j-in-tile], 128B rows
    __shared__ __align__(16) short Pw[4][16 * 64];     // per-wave, swizzled

    const short* qTb = qT + (size_t)b * NPOS * CDIM;
    const char*  kTB = (const char*)(kT + (size_t)b * NPOS * CDIM);
    const char*  vB  = (const char*)(vM + (size_t)b * CDIM * NPOS);

    const int i0 = rb * RPB + wave * 16;

    // stage tile tt into buf[tt&1]: LDS[r*128+o] = G[r][o ^ ((r&7)<<4)]
    auto stage = [&](int tt) {
        const int j0 = jc * JCHUNK + tt * 64;
        const char* kS = kTB + (size_t)j0 * (CDIM * 2);
        const char* vS = vB  + (size_t)j0 * 2;
        char* kD = (char*)&Kbuf[tt & 1][0];
        char* vD = (char*)&Vbuf[tt & 1][0];
        #pragma unroll
        for (int i = 0; i < 2; ++i) {
            const int base = wave * 2048 + i * 1024;   // wave-uniform LDS dest
            const int L    = base + lane * 16;         // linear LDS offset
            const int r    = L >> 7;                   // tile row
            const int o    = (L & 127) ^ ((r & 7) << 4);
            gload16(kS + (size_t)((L & ~127) + o), kD + base);
            gload16(vS + (size_t)r * (NPOS * 2) + o, vD + base);
        }
    };

    bf16x8 qf[2];
    {
        const short* qp = qTb + (size_t)(i0 + col) * CDIM + quad * 8;
        qf[0] = *(const bf16x8*)qp;
        qf[1] = *(const bf16x8*)(qp + 32);
    }

    f32x4 oacc[4];
    #pragma unroll
    for (int cb = 0; cb < 4; ++cb) oacc[cb] = (f32x4){0.f, 0.f, 0.f, 0.f};
    float lp = 0.f;

    char* Pc = (char*)&Pw[wave][0];
    const int pswz = (col & 7) << 4;                   // row swizzle (row = col)
    const int slot = (quad * 16) ^ pswz;               // swizzled 16B read slot

    stage(0);
    __syncthreads();                                   // buf0 staged

    for (int tt = 0; tt < NTILE; ++tt) {
        if (tt + 1 < NTILE) stage(tt + 1);             // loads fly under compute

        const char* Kc = (const char*)&Kbuf[tt & 1][0];
        const char* Vc = (const char*)&Vbuf[tt & 1][0];

        // ---- S^T = K.Q^T, exp, pack, stash (b64 DS writes, swizzled) ----
        #pragma unroll
        for (int ct = 0; ct < 4; ++ct) {
            const char* kr = Kc + (ct * 16 + col) * 128;
            bf16x8 k0 = *(const bf16x8*)(kr + slot);
            bf16x8 k1 = *(const bf16x8*)(kr + (slot ^ 64));
            f32x4 a = (f32x4){0.f, 0.f, 0.f, 0.f};
            __builtin_amdgcn_s_setprio(1);
            a = __builtin_amdgcn_mfma_f32_16x16x32_bf16(k0, qf[0], a, 0, 0, 0);
            a = __builtin_amdgcn_mfma_f32_16x16x32_bf16(k1, qf[1], a, 0, 0, 0);
            __builtin_amdgcn_s_setprio(0);
            float p0 = __expf(a[0]), p1 = __expf(a[1]);
            float p2 = __expf(a[2]), p3 = __expf(a[3]);
            lp += (p0 + p1) + (p2 + p3);
            *(short4b*)(Pc + col * 128 + ((ct * 32 + quad * 8) ^ pswz)) =
                (short4b){f2bs(p0), f2bs(p1), f2bs(p2), f2bs(p3)};
        }

        // ---- P fragments back (same-wave DS, same-elem-type aliasing) ----
        bf16x8 pf0 = *(const bf16x8*)(Pc + col * 128 + slot);
        bf16x8 pf1 = *(const bf16x8*)(Pc + col * 128 + (slot ^ 64));

        // ---- O^T += V^T . P^T (V from LDS, swizzled reads) ----
        #pragma unroll
        for (int cb = 0; cb < 4; ++cb) {
            const char* vr = Vc + (cb * 16 + col) * 128;
            bf16x8 v0 = *(const bf16x8*)(vr + slot);
            bf16x8 v1 = *(const bf16x8*)(vr + (slot ^ 64));
            __builtin_amdgcn_s_setprio(1);
            oacc[cb] = __builtin_amdgcn_mfma_f32_16x16x32_bf16(v0, pf0, oacc[cb], 0, 0, 0);
            oacc[cb] = __builtin_amdgcn_mfma_f32_16x16x32_bf16(v1, pf1, oacc[cb], 0, 0, 0);
            __builtin_amdgcn_s_setprio(0);
        }
        __syncthreads();   // drains stage(tt+1) loads + closes tile
    }

    lp += __shfl_xor(lp, 16, 64);
    lp += __shfl_xor(lp, 32, 64);
    if (quad == 0)
        lacc[(size_t)(jc * BATCH + b) * NPOS + i0 + col] = lp;

    unsigned short* Ob = Opart + (size_t)(jc * BATCH + b) * CDIM * NPOS;
    #pragma unroll
    for (int cb = 0; cb < 4; ++cb)
        #pragma unroll
        for (int r = 0; r < 4; ++r)
            Ob[(size_t)(cb * 16 + quad * 4 + r) * NPOS + i0 + col] =
                (unsigned short)f2bs(oacc[cb][r]);

    // ---------------- fused combine tail (last block of group) ----------
    __syncthreads();                        // all stores issued (vmcnt drained)
    int* flag = (int*)&Pw[2][0];            // Pw is dead; alias LDS
    if (t == 0) {
        __threadfence();                    // release: wb this XCD's L2
        *flag = atomicAdd(&cnt[b * 64 + rb], 1);
    }
    __syncthreads();
    if (*flag == JSPLIT - 1) {
        __threadfence();                    // acquire: inv local L2/L1
        float* linv_s = (float*)&Pw[0][0];
        const int ib = rb * RPB;
        if (t < RPB) {
            float s = 0.f;
            #pragma unroll
            for (int j2 = 0; j2 < JSPLIT; ++j2)
                s += lacc[(size_t)(j2 * BATCH + b) * NPOS + ib + t];
            linv_s[t] = gamma[0] / s;
        }
        __syncthreads();
        const int c = t >> 2, r0 = (t & 3) * 16;
        float acc2[16];
        #pragma unroll
        for (int k = 0; k < 16; ++k) acc2[k] = 0.f;
        #pragma unroll
        for (int j2 = 0; j2 < JSPLIT; ++j2) {
            const unsigned short* Ob2 = Opart +
                ((size_t)(j2 * BATCH + b) * CDIM + c) * NPOS + ib + r0;
            u32x4 w0 = *(const u32x4*)Ob2;
            u32x4 w1 = *(const u32x4*)(Ob2 + 8);
            #pragma unroll
            for (int j = 0; j < 4; ++j) {
                acc2[2 * j]     += bffloat(w0[j] << 16);
                acc2[2 * j + 1] += bffloat(w0[j] & 0xffff0000u);
                acc2[8 + 2 * j] += bffloat(w1[j] << 16);
                acc2[9 + 2 * j] += bffloat(w1[j] & 0xffff0000u);
            }
        }
        const float* xb = x + ((size_t)b * CDIM + c) * NPOS + ib + r0;
        float* ob = out + ((size_t)b * CDIM + c) * NPOS + ib + r0;
        #pragma unroll
        for (int k = 0; k < 4; ++k) {
            f32x4 x4 = *(const f32x4*)(xb + k * 4);
            f32x4 r;
            #pragma unroll
            for (int j = 0; j < 4; ++j)
                r[j] = fmaf(acc2[k * 4 + j], linv_s[r0 + k * 4 + j], x4[j]);
            *(f32x4*)(ob + k * 4) = r;
        }
    }
}

extern "C" void kernel_launch(void* const* d_in, const int* in_sizes, int n_in,
                              void* d_out, int out_size, void* d_ws, size_t ws_size,
                              hipStream_t stream) {
    const float* x     = (const float*)d_in[0];
    const float* q_dw  = (const float*)d_in[1];
    const float* q_pw  = (const float*)d_in[2];
    const float* k_dw  = (const float*)d_in[3];
    const float* k_pw  = (const float*)d_in[4];
    const float* v_dw  = (const float*)d_in[5];
    const float* v_pw  = (const float*)d_in[6];
    const float* gamma = (const float*)d_in[7];
    float* out = (float*)d_out;

    // ws: qT 1M | kT 1M | vM 1M | Opart 8.4M | lacc 256K | cnt @12M
    char* ws = (char*)d_ws;
    short* qT             = (short*)(ws);
    short* kT             = (short*)(ws + (1u << 20));
    short* vM             = (short*)(ws + (2u << 20));
    unsigned short* Opart = (unsigned short*)(ws + (3u << 20));
    float* lacc           = (float*)(ws + (3u << 20) +
                                     (size_t)JSPLIT * BATCH * CDIM * NPOS * 2);
    int* cnt              = (int*)(ws + (12u << 20));

    qkv_kernel<<<3 * BATCH * 256, 64, 0, stream>>>(
        x, q_dw, q_pw, k_dw, k_pw, v_dw, v_pw, qT, kT, vM, cnt);
    attn_kernel<<<ATTN_GRID, 256, 0, stream>>>(qT, kT, vM, Opart, lacc,
                                               cnt, x, gamma, out);
}

// Round 6
// 97.363 us; speedup vs baseline: 1.7723x; 1.7723x over previous
//
#include <hip/hip_runtime.h>
#include <hip/hip_bf16.h>

#define NPOS 4096
#define CDIM 64
#define BATCH 2
#define JSPLIT 8                  // j-range split; Opart = 8.4 MB bf16
#define JSHIFT 3                  // log2(JSPLIT)
#define JCHUNK (NPOS / JSPLIT)    // 512 j per block (8 tiles of 64)
#define NTILE (JCHUNK / 64)       // 8 pipelined tiles
#define RPB 128                   // q-rows per block (4 waves x 32 rows)
#define ATTN_GRID (BATCH * (NPOS / RPB) * JSPLIT)   // 512 blocks

typedef __attribute__((ext_vector_type(8))) short bf16x8;
typedef __attribute__((ext_vector_type(4))) short short4b;
typedef __attribute__((ext_vector_type(4))) float f32x4;
typedef __attribute__((ext_vector_type(4))) unsigned int u32x4;
typedef __attribute__((ext_vector_type(2))) unsigned int u32x2;

static __device__ __forceinline__ unsigned int fbits(float f) {
    union { float f; unsigned int u; } v; v.f = f; return v.u;
}
static __device__ __forceinline__ float bffloat(unsigned int hi16) {
    union { unsigned int u; float f; } v; v.u = hi16; return v.f;
}
static __device__ __forceinline__ unsigned int pk2bf(float a, float b) {
    return ((fbits(a) + 0x8000u) >> 16) | ((fbits(b) + 0x8000u) & 0xffff0000u);
}
static __device__ __forceinline__ short f2bs(float f) {
    return (short)(unsigned short)((fbits(f) + 0x8000u) >> 16);
}

// async global->LDS, 16B per lane; LDS dest = wave-uniform base + lane*16,
// global src is per-lane (carries the XOR swizzle).
static __device__ __forceinline__ void gload16(const void* g, void* l) {
    __builtin_amdgcn_global_load_lds(
        (const __attribute__((address_space(1))) unsigned int*)g,
        (__attribute__((address_space(3))) unsigned int*)l, 16, 0, 0);
}

// ---------------------------------------------------------------------------
// Kernel 1: qkv with weff fused in-register (verified; byte-identical to R2).
// MFMA 16x16x32 bf16 layouts (HW-verified):
//   A[m=lane&15][k=quad*8+j]  B[k=quad*8+j][n=lane&15]  C/D[quad*4+r][lane&15]
// ---------------------------------------------------------------------------
__global__ __launch_bounds__(64) void qkv_kernel(
    const float* __restrict__ x,
    const float* __restrict__ q_dw, const float* __restrict__ q_pw,
    const float* __restrict__ k_dw, const float* __restrict__ k_pw,
    const float* __restrict__ v_dw, const float* __restrict__ v_pw,
    short* __restrict__ qT, short* __restrict__ kT, short* __restrict__ vM)
{
    const int bid  = blockIdx.x;
    const int p    = bid >> 9;          // 0=q 1=k 2=v
    const int np   = bid & 511;
    const int b    = np >> 8;
    const int n0   = (np & 255) << 4;
    const int lane = threadIdx.x;
    const int col  = lane & 15;
    const int quad = lane >> 4;
    const int n    = n0 + col;

    const float* pw = (p == 0) ? q_pw : (p == 1) ? k_pw : v_pw;
    const float* dw = (p == 0) ? q_dw : (p == 1) ? k_dw : v_dw;

    bf16x8 xf0, xf1;
    float dv0[8], dv1[8];
    #pragma unroll
    for (int j = 0; j < 8; ++j) {
        xf0[j] = f2bs(x[(size_t)(b * CDIM + quad * 8 + j) * NPOS + n]);
        xf1[j] = f2bs(x[(size_t)(b * CDIM + 32 + quad * 8 + j) * NPOS + n]);
        dv0[j] = dw[quad * 8 + j];
        dv1[j] = dw[32 + quad * 8 + j];
    }

    #pragma unroll
    for (int os = 0; os < 4; ++os) {
        const float* pr = pw + (os * 16 + col) * 64 + quad * 8;
        bf16x8 wf0, wf1;
        #pragma unroll
        for (int j = 0; j < 8; ++j) {
            wf0[j] = f2bs(pr[j] * dv0[j]);
            wf1[j] = f2bs(pr[32 + j] * dv1[j]);
        }
        f32x4 d = (f32x4){0.f, 0.f, 0.f, 0.f};
        if (p < 2) {
            d = __builtin_amdgcn_mfma_f32_16x16x32_bf16(wf0, xf0, d, 0, 0, 0);
            d = __builtin_amdgcn_mfma_f32_16x16x32_bf16(wf1, xf1, d, 0, 0, 0);
            short* dst = p ? kT : qT;
            *(u32x2*)(dst + (size_t)(b * NPOS + n) * CDIM + os * 16 + quad * 4) =
                (u32x2){pk2bf(d[0], d[1]), pk2bf(d[2], d[3])};
        } else {
            d = __builtin_amdgcn_mfma_f32_16x16x32_bf16(xf0, wf0, d, 0, 0, 0);
            d = __builtin_amdgcn_mfma_f32_16x16x32_bf16(xf1, wf1, d, 0, 0, 0);
            *(u32x2*)(vM + (size_t)(b * CDIM + os * 16 + col) * NPOS + n0 + quad * 4) =
                (u32x2){pk2bf(d[0], d[1]), pk2bf(d[2], d[3])};
        }
    }
}

// ---------------------------------------------------------------------------
// Kernel 2: flash attention v7 — LDS-traffic-halved via 2x row blocking.
// R4/R5 established attn is LDS-BW-bound per CU (per-pass LDS bytes / 78
// TB/s ~= measured 12us steady pass; TLP doubling R1->R2 was flat). Fix:
// each wave owns 32 q-rows (rs=0,1), so each K/V LDS read (8+8 KB/tile)
// serves 2x the MACs -> per-pass LDS traffic ~0.6x. Composition of two
// verified pieces: R1's 2-rs register structure (qf[2][2], oacc[2][4],
// lp[2], verified at RPB=128) + R2's staging/swizzle (verified). P buffer
// per wave = 32 rows, same (row&7)=(col&7) swizzle family. LDS = 16K(K) +
// 16K(V) + 16K(P) = 48K -> 3 blocks/CU cap; grid 512 = 2/CU resident.
// NO cross-block sync of any kind (R3/R5 lessons).
// ---------------------------------------------------------------------------
__global__ __launch_bounds__(256, 3) void attn_kernel(
    const short* __restrict__ qT, const short* __restrict__ kT,
    const short* __restrict__ vM,
    unsigned short* __restrict__ Opart, float* __restrict__ lacc)
{
    const int gid  = blockIdx.x;
    const int jc   = gid & (JSPLIT - 1);
    const int rb   = (gid >> JSHIFT) & 31;
    const int b    = gid >> (JSHIFT + 5);
    const int t    = threadIdx.x;
    const int wave = t >> 6;
    const int lane = t & 63;
    const int col  = lane & 15;
    const int quad = lane >> 4;

    __shared__ __align__(16) short Kbuf[2][64 * 64];   // [j-in-tile][ch], 128B rows
    __shared__ __align__(16) short Vbuf[2][64 * 64];   // [ch][j-in-tile], 128B rows
    __shared__ __align__(16) short Pw[4][32 * 64];     // per-wave 32 rows, swizzled

    const short* qTb = qT + (size_t)b * NPOS * CDIM;
    const char*  kTB = (const char*)(kT + (size_t)b * NPOS * CDIM);
    const char*  vB  = (const char*)(vM + (size_t)b * CDIM * NPOS);

    const int i0 = rb * RPB + wave * 32;

    // stage tile tt into buf[tt&1]: LDS[r*128+o] = G[r][o ^ ((r&7)<<4)]
    // (swizzle carried on the per-lane GLOBAL src; LDS write is linear).
    auto stage = [&](int tt) {
        const int j0 = jc * JCHUNK + tt * 64;
        const char* kS = kTB + (size_t)j0 * (CDIM * 2);
        const char* vS = vB  + (size_t)j0 * 2;
        char* kD = (char*)&Kbuf[tt & 1][0];
        char* vD = (char*)&Vbuf[tt & 1][0];
        #pragma unroll
        for (int i = 0; i < 2; ++i) {
            const int base = wave * 2048 + i * 1024;   // wave-uniform LDS dest
            const int L    = base + lane * 16;         // linear LDS offset
            const int r    = L >> 7;                   // tile row
            const int o    = (L & 127) ^ ((r & 7) << 4);
            gload16(kS + (size_t)((L & ~127) + o), kD + base);
            gload16(vS + (size_t)r * (NPOS * 2) + o, vD + base);
        }
    };

    bf16x8 qf[2][2];
    #pragma unroll
    for (int rs = 0; rs < 2; ++rs) {
        const short* qp = qTb + (size_t)(i0 + rs * 16 + col) * CDIM + quad * 8;
        qf[rs][0] = *(const bf16x8*)qp;
        qf[rs][1] = *(const bf16x8*)(qp + 32);
    }

    f32x4 oacc[2][4];
    #pragma unroll
    for (int rs = 0; rs < 2; ++rs)
        #pragma unroll
        for (int cb = 0; cb < 4; ++cb) oacc[rs][cb] = (f32x4){0.f, 0.f, 0.f, 0.f};
    float lp[2] = {0.f, 0.f};

    char* Pc = (char*)&Pw[wave][0];
    const int pswz = (col & 7) << 4;                   // row swizzle (row&7 = col&7)
    const int slot = (quad * 16) ^ pswz;               // swizzled 16B read slot

    stage(0);
    __syncthreads();                                   // buf0 staged

    for (int tt = 0; tt < NTILE; ++tt) {
        if (tt + 1 < NTILE) stage(tt + 1);             // loads fly under compute

        const char* Kc = (const char*)&Kbuf[tt & 1][0];
        const char* Vc = (const char*)&Vbuf[tt & 1][0];

        // ---- S^T = K.Q^T, exp, pack, stash; K reads amortized over 2 rs ----
        #pragma unroll
        for (int ct = 0; ct < 4; ++ct) {
            const char* kr = Kc + (ct * 16 + col) * 128;
            bf16x8 k0 = *(const bf16x8*)(kr + slot);
            bf16x8 k1 = *(const bf16x8*)(kr + (slot ^ 64));
            #pragma unroll
            for (int rs = 0; rs < 2; ++rs) {
                f32x4 a = (f32x4){0.f, 0.f, 0.f, 0.f};
                __builtin_amdgcn_s_setprio(1);
                a = __builtin_amdgcn_mfma_f32_16x16x32_bf16(k0, qf[rs][0], a, 0, 0, 0);
                a = __builtin_amdgcn_mfma_f32_16x16x32_bf16(k1, qf[rs][1], a, 0, 0, 0);
                __builtin_amdgcn_s_setprio(0);
                float p0 = __expf(a[0]), p1 = __expf(a[1]);
                float p2 = __expf(a[2]), p3 = __expf(a[3]);
                lp[rs] += (p0 + p1) + (p2 + p3);
                *(short4b*)(Pc + (rs * 16 + col) * 128 + ((ct * 32 + quad * 8) ^ pswz)) =
                    (short4b){f2bs(p0), f2bs(p1), f2bs(p2), f2bs(p3)};
            }
        }

        // ---- P fragments back (same-wave DS, same-elem-type aliasing) ----
        bf16x8 pf[2][2];
        #pragma unroll
        for (int rs = 0; rs < 2; ++rs) {
            pf[rs][0] = *(const bf16x8*)(Pc + (rs * 16 + col) * 128 + slot);
            pf[rs][1] = *(const bf16x8*)(Pc + (rs * 16 + col) * 128 + (slot ^ 64));
        }

        // ---- O^T += V^T . P^T; V reads amortized over 2 rs ----
        #pragma unroll
        for (int cb = 0; cb < 4; ++cb) {
            const char* vr = Vc + (cb * 16 + col) * 128;
            bf16x8 v0 = *(const bf16x8*)(vr + slot);
            bf16x8 v1 = *(const bf16x8*)(vr + (slot ^ 64));
            __builtin_amdgcn_s_setprio(1);
            #pragma unroll
            for (int rs = 0; rs < 2; ++rs) {
                oacc[rs][cb] = __builtin_amdgcn_mfma_f32_16x16x32_bf16(v0, pf[rs][0], oacc[rs][cb], 0, 0, 0);
                oacc[rs][cb] = __builtin_amdgcn_mfma_f32_16x16x32_bf16(v1, pf[rs][1], oacc[rs][cb], 0, 0, 0);
            }
            __builtin_amdgcn_s_setprio(0);
        }
        __syncthreads();   // drains stage(tt+1) loads + closes tile
    }

    #pragma unroll
    for (int rs = 0; rs < 2; ++rs) {
        lp[rs] += __shfl_xor(lp[rs], 16, 64);
        lp[rs] += __shfl_xor(lp[rs], 32, 64);
    }
    if (quad == 0) {
        #pragma unroll
        for (int rs = 0; rs < 2; ++rs)
            lacc[(size_t)(jc * BATCH + b) * NPOS + i0 + rs * 16 + col] = lp[rs];
    }

    unsigned short* Ob = Opart + (size_t)(jc * BATCH + b) * CDIM * NPOS;
    #pragma unroll
    for (int rs = 0; rs < 2; ++rs)
        #pragma unroll
        for (int cb = 0; cb < 4; ++cb)
            #pragma unroll
            for (int r = 0; r < 4; ++r)
                Ob[(size_t)(cb * 16 + quad * 4 + r) * NPOS + i0 + rs * 16 + col] =
                    (unsigned short)f2bs(oacc[rs][cb][r]);
}

// ---------------------------------------------------------------------------
// Kernel 3: out = gamma/lsum * sum_jc Opart + x  (verified body; JSPLIT=8)
// ---------------------------------------------------------------------------
__global__ __launch_bounds__(256) void combine_kernel(
    const unsigned short* __restrict__ Opart, const float* __restrict__ lacc,
    const float* __restrict__ x, const float* __restrict__ gamma,
    float* __restrict__ out)
{
    int b  = blockIdx.x >> 7;
    int n0 = (blockIdx.x & 127) << 5;
    __shared__ float linv[32];
    int t = threadIdx.x;
    if (t < 32) {
        float s = 0.f;
        #pragma unroll
        for (int jc = 0; jc < JSPLIT; ++jc)
            s += lacc[(size_t)(jc * BATCH + b) * NPOS + n0 + t];
        linv[t] = gamma[0] / s;
    }
    __syncthreads();

    int c = t >> 2, ns = (t & 3) * 8;
    float acc[8];
    #pragma unroll
    for (int k = 0; k < 8; ++k) acc[k] = 0.f;
    #pragma unroll
    for (int jc = 0; jc < JSPLIT; ++jc) {
        const unsigned short* Ob = Opart + ((size_t)(jc * BATCH + b) * CDIM + c) * NPOS + n0 + ns;
        u32x4 w = *(const u32x4*)Ob;
        #pragma unroll
        for (int j = 0; j < 4; ++j) {
            acc[2 * j]     += bffloat(w[j] << 16);
            acc[2 * j + 1] += bffloat(w[j] & 0xffff0000u);
        }
    }
    const float* xb = x + ((size_t)b * CDIM + c) * NPOS + n0 + ns;
    float* ob = out + ((size_t)b * CDIM + c) * NPOS + n0 + ns;
    #pragma unroll
    for (int k = 0; k < 2; ++k) {
        f32x4 x4 = *(const f32x4*)(xb + k * 4);
        f32x4 r;
        #pragma unroll
        for (int j = 0; j < 4; ++j)
            r[j] = fmaf(acc[k * 4 + j], linv[ns + k * 4 + j], x4[j]);
        *(f32x4*)(ob + k * 4) = r;
    }
}

extern "C" void kernel_launch(void* const* d_in, const int* in_sizes, int n_in,
                              void* d_out, int out_size, void* d_ws, size_t ws_size,
                              hipStream_t stream) {
    const float* x     = (const float*)d_in[0];
    const float* q_dw  = (const float*)d_in[1];
    const float* q_pw  = (const float*)d_in[2];
    const float* k_dw  = (const float*)d_in[3];
    const float* k_pw  = (const float*)d_in[4];
    const float* v_dw  = (const float*)d_in[5];
    const float* v_pw  = (const float*)d_in[6];
    const float* gamma = (const float*)d_in[7];
    float* out = (float*)d_out;

    // ws: qT 1M | kT 1M | vM 1M | Opart 8.4M | lacc 256K
    char* ws = (char*)d_ws;
    short* qT             = (short*)(ws);
    short* kT             = (short*)(ws + (1u << 20));
    short* vM             = (short*)(ws + (2u << 20));
    unsigned short* Opart = (unsigned short*)(ws + (3u << 20));
    float* lacc           = (float*)(ws + (3u << 20) +
                                     (size_t)JSPLIT * BATCH * CDIM * NPOS * 2);

    qkv_kernel<<<3 * BATCH * 256, 64, 0, stream>>>(
        x, q_dw, q_pw, k_dw, k_pw, v_dw, v_pw, qT, kT, vM);
    attn_kernel<<<ATTN_GRID, 256, 0, stream>>>(qT, kT, vM, Opart, lacc);
    combine_kernel<<<BATCH * 128, 256, 0, stream>>>(Opart, lacc, x, gamma, out);
}